// Round 7
// baseline (155.847 us; speedup 1.0000x reference)
//
#include <hip/hip_runtime.h>
#include <math.h>
#include <stdint.h>

#define BDIM 8
#define TDIM 2048
#define EDIM 1024
#define HDIM 64
#define NCHUNK 144   // sum over iq of ceil((iq+1)/4), iq in [0,32)

typedef short bf16x8 __attribute__((ext_vector_type(8)));   // 8 bf16 (4 VGPRs)
typedef float f32x4 __attribute__((ext_vector_type(4)));    // 4 fp32 acc

__device__ __forceinline__ unsigned short f2bf(float f) {   // RNE fp32->bf16
    uint32_t u = __builtin_bit_cast(uint32_t, f);
    u += 0x7fffu + ((u >> 16) & 1u);
    return (unsigned short)(u >> 16);
}
__device__ __forceinline__ float bf2f(unsigned short s) {
    uint32_t u = ((uint32_t)s) << 16;
    return __builtin_bit_cast(float, u);
}

// ---------------------------------------------------------------------------
// prep_w: W[e][h] fp32 -> WT[h][e] bf16  (row-contiguous 16B staging loads)
// ---------------------------------------------------------------------------
__global__ __launch_bounds__(256) void prep_w(
    const float* __restrict__ Wq, const float* __restrict__ Wk,
    const float* __restrict__ Wv,
    unsigned short* __restrict__ WqT, unsigned short* __restrict__ WkT,
    unsigned short* __restrict__ WvT)
{
    int id = blockIdx.x * 256 + threadIdx.x;   // 0..65535
    int e = id >> 6, h = id & 63;              // coalesced reads
    int oi = h * EDIM + e;
    WqT[oi] = f2bf(Wq[id]);
    WkT[oi] = f2bf(Wk[id]);
    WvT[oi] = f2bf(Wv[id]);
}

// ---------------------------------------------------------------------------
// proj (split by output): grid 768 = (row-tile 256) x (which 3, interleaved
// so same-row blocks run concurrently and share x via L2/L3).
// One W tile per block -> LDS 36.9 KB (4 blocks/CU), one acc set -> low
// VGPR.  Double-buffered LDS, register prefetch, ONE barrier/iter.
// which: 0=Q (row-major), 1=K (row-major), 2=V (transposed [b][d][T]).
// ---------------------------------------------------------------------------
__global__ __launch_bounds__(256) void proj_kernel(
    const float* __restrict__ x,
    const unsigned short* __restrict__ WqT, const unsigned short* __restrict__ WkT,
    const unsigned short* __restrict__ WvT,
    const float* __restrict__ bq, const float* __restrict__ bk,
    const float* __restrict__ bv,
    unsigned short* __restrict__ Qb, unsigned short* __restrict__ Kb,
    unsigned short* __restrict__ VbT)
{
    __shared__ unsigned short Xs[2][64][72];   // row stride 144B (16B mult)
    __shared__ unsigned short Ws[2][64][72];

    const int t = threadIdx.x;
    const int lane = t & 63, w = t >> 6, quad = lane >> 4, ln = lane & 15;
    const int which = blockIdx.x % 3;
    const int row0  = (blockIdx.x / 3) * 64;
    const int sr = t >> 2;              // staging row 0..63
    const int sc = (t & 3) << 4;        // staging col 0,16,32,48

    const unsigned short* WT = (which == 0) ? WqT : (which == 1) ? WkT : WvT;
    const float* bias        = (which == 0) ? bq  : (which == 1) ? bk  : bv;

    f32x4 acc[4];
#pragma unroll
    for (int j = 0; j < 4; ++j) acc[j] = (f32x4)(0.f);

    const float* xp0  = &x[(size_t)(row0 + sr) * EDIM + sc];
    const size_t wrow = (size_t)sr * EDIM + sc;

    // ---- preload tile 0 into buf 0 ----
    {
        float4 x0 = *(const float4*)(xp0);
        float4 x1 = *(const float4*)(xp0 + 4);
        float4 x2 = *(const float4*)(xp0 + 8);
        float4 x3 = *(const float4*)(xp0 + 12);
        bf16x8 xb0, xb1;
        xb0[0]=(short)f2bf(x0.x); xb0[1]=(short)f2bf(x0.y); xb0[2]=(short)f2bf(x0.z); xb0[3]=(short)f2bf(x0.w);
        xb0[4]=(short)f2bf(x1.x); xb0[5]=(short)f2bf(x1.y); xb0[6]=(short)f2bf(x1.z); xb0[7]=(short)f2bf(x1.w);
        xb1[0]=(short)f2bf(x2.x); xb1[1]=(short)f2bf(x2.y); xb1[2]=(short)f2bf(x2.z); xb1[3]=(short)f2bf(x2.w);
        xb1[4]=(short)f2bf(x3.x); xb1[5]=(short)f2bf(x3.y); xb1[6]=(short)f2bf(x3.z); xb1[7]=(short)f2bf(x3.w);
        *(bf16x8*)&Xs[0][sr][sc]     = xb0;
        *(bf16x8*)&Xs[0][sr][sc + 8] = xb1;
        *(bf16x8*)&Ws[0][sr][sc]     = *(const bf16x8*)&WT[wrow];
        *(bf16x8*)&Ws[0][sr][sc + 8] = *(const bf16x8*)&WT[wrow + 8];
    }

    for (int kt = 0; kt < EDIM / 64; ++kt) {
        const int cur = kt & 1, nxt = cur ^ 1;

        // ---- issue next-tile global loads (in flight during MFMA) ----
        float4 x0, x1, x2, x3;
        bf16x8 wv0, wv1;
        if (kt < 15) {
            const float* xp = xp0 + (kt + 1) * 64;
            x0 = *(const float4*)(xp);
            x1 = *(const float4*)(xp + 4);
            x2 = *(const float4*)(xp + 8);
            x3 = *(const float4*)(xp + 12);
            const size_t wo = wrow + (kt + 1) * 64;
            wv0 = *(const bf16x8*)&WT[wo];
            wv1 = *(const bf16x8*)&WT[wo + 8];
        }

        __syncthreads();   // buf[cur] fully written (prev iter / preload)

        bf16x8 xa0 = *(const bf16x8*)&Xs[cur][16 * w + ln][8 * quad];
        bf16x8 xa1 = *(const bf16x8*)&Xs[cur][16 * w + ln][32 + 8 * quad];
#pragma unroll
        for (int j = 0; j < 4; ++j) {
            bf16x8 w0 = *(const bf16x8*)&Ws[cur][16 * j + ln][8 * quad];
            bf16x8 w1 = *(const bf16x8*)&Ws[cur][16 * j + ln][32 + 8 * quad];
            acc[j] = __builtin_amdgcn_mfma_f32_16x16x32_bf16(xa0, w0, acc[j], 0, 0, 0);
            acc[j] = __builtin_amdgcn_mfma_f32_16x16x32_bf16(xa1, w1, acc[j], 0, 0, 0);
        }

        // ---- convert + write next tile to alternate buffer ----
        if (kt < 15) {
            bf16x8 xb0, xb1;
            xb0[0]=(short)f2bf(x0.x); xb0[1]=(short)f2bf(x0.y); xb0[2]=(short)f2bf(x0.z); xb0[3]=(short)f2bf(x0.w);
            xb0[4]=(short)f2bf(x1.x); xb0[5]=(short)f2bf(x1.y); xb0[6]=(short)f2bf(x1.z); xb0[7]=(short)f2bf(x1.w);
            xb1[0]=(short)f2bf(x2.x); xb1[1]=(short)f2bf(x2.y); xb1[2]=(short)f2bf(x2.z); xb1[3]=(short)f2bf(x2.w);
            xb1[4]=(short)f2bf(x3.x); xb1[5]=(short)f2bf(x3.y); xb1[6]=(short)f2bf(x3.z); xb1[7]=(short)f2bf(x3.w);
            *(bf16x8*)&Xs[nxt][sr][sc]     = xb0;
            *(bf16x8*)&Xs[nxt][sr][sc + 8] = xb1;
            *(bf16x8*)&Ws[nxt][sr][sc]     = wv0;
            *(bf16x8*)&Ws[nxt][sr][sc + 8] = wv1;
        }
    }

    // epilogue: bias + bf16 store (C/D layout: row=4*quad+reg, col=ln+16j)
#pragma unroll
    for (int j = 0; j < 4; ++j) {
        int col = 16 * j + ln;
        float bv_ = bias[col];
#pragma unroll
        for (int r = 0; r < 4; ++r) {
            size_t row = (size_t)(row0 + 16 * w + 4 * quad + r);
            unsigned short val = f2bf(acc[j][r] + bv_);
            if (which == 0) {
                Qb[row * HDIM + col] = val;
            } else if (which == 1) {
                Kb[row * HDIM + col] = val;
            } else {
                int bb = (int)(row >> 11);            // row / TDIM
                int tr = (int)(row & 2047);           // row % TDIM
                VbT[((size_t)bb * HDIM + col) * TDIM + tr] = val;
            }
        }
    }
}

// ---------------------------------------------------------------------------
// Split-K flash partial.  Grid (NCHUNK=144, B).  LDS-staged K/V (coalesced
// 16B loads — direct-global frag gathers measurably regress).
// Partials PO stored bf16 (halves PO traffic; error ~0.4% rel, within budget)
// ---------------------------------------------------------------------------
__global__ __launch_bounds__(256) void attn_partial(
    const unsigned short* __restrict__ Qb, const unsigned short* __restrict__ Kb,
    const unsigned short* __restrict__ VbT,
    unsigned short* __restrict__ PO, float* __restrict__ Pm, float* __restrict__ Pl)
{
    __shared__ unsigned short Ks[64][72];
    __shared__ unsigned short VsT[64][72];   // [d][k]
    __shared__ unsigned short Ps[64][72];    // [q][k] bf16

    const int t = threadIdx.x;
    const int lane = t & 63, w = t >> 6, quad = lane >> 4, ln = lane & 15;
    const int f = blockIdx.x;
    const int b = blockIdx.y;

    // decode (iq, chunk) from f: group g = iq>>2 has (g+1) chunks/q-tile
    int g = 0;
    while (f >= 2 * (g + 1) * (g + 2)) ++g;       // g in 0..7
    const int r_  = f - 2 * g * (g + 1);
    const int iq  = 4 * g + r_ / (g + 1);
    const int ch  = r_ % (g + 1);

    const int q0 = iq * 64;
    const size_t base = (size_t)b * TDIM * HDIM;
    const int sr = t >> 2;
    const int sc = (t & 3) << 4;

    const size_t qrow = base + (size_t)(q0 + 16 * w + ln) * HDIM;
    bf16x8 qa0 = *(const bf16x8*)&Qb[qrow + 8 * quad];
    bf16x8 qa1 = *(const bf16x8*)&Qb[qrow + 32 + 8 * quad];

    f32x4 od[4];
#pragma unroll
    for (int j = 0; j < 4; ++j) od[j] = (f32x4)(0.f);
    float mrow[4], lrow[4];
#pragma unroll
    for (int r = 0; r < 4; ++r) { mrow[r] = -INFINITY; lrow[r] = 0.f; }

    const float scale = 0.125f;   // 1/sqrt(64)
    int j1 = 4 * ch + 3; if (j1 > iq) j1 = iq;

    for (int jt = 4 * ch; jt <= j1; ++jt) {
        __syncthreads();
        {
            size_t ko = base + (size_t)(jt * 64 + sr) * HDIM + sc;
            *(bf16x8*)&Ks[sr][sc]     = *(const bf16x8*)&Kb[ko];
            *(bf16x8*)&Ks[sr][sc + 8] = *(const bf16x8*)&Kb[ko + 8];
            const unsigned short* vrow =
                &VbT[((size_t)b * HDIM + sr) * TDIM + jt * 64 + sc];
            *(bf16x8*)&VsT[sr][sc]     = *(const bf16x8*)vrow;
            *(bf16x8*)&VsT[sr][sc + 8] = *(const bf16x8*)(vrow + 8);
        }
        __syncthreads();

        // ---- S = Q K^T ----
        f32x4 s[4];
#pragma unroll
        for (int j = 0; j < 4; ++j) {
            bf16x8 kb0 = *(const bf16x8*)&Ks[16 * j + ln][8 * quad];
            bf16x8 kb1 = *(const bf16x8*)&Ks[16 * j + ln][32 + 8 * quad];
            s[j] = (f32x4)(0.f);
            s[j] = __builtin_amdgcn_mfma_f32_16x16x32_bf16(qa0, kb0, s[j], 0, 0, 0);
            s[j] = __builtin_amdgcn_mfma_f32_16x16x32_bf16(qa1, kb1, s[j], 0, 0, 0);
        }

        // ---- scale + causal mask (diagonal tile only) ----
        if (jt == iq) {
#pragma unroll
            for (int j = 0; j < 4; ++j) {
                int kg = jt * 64 + 16 * j + ln;
#pragma unroll
                for (int r = 0; r < 4; ++r) {
                    int qg = q0 + 16 * w + 4 * quad + r;
                    s[j][r] = (kg <= qg) ? s[j][r] * scale : -INFINITY;
                }
            }
        } else {
#pragma unroll
            for (int j = 0; j < 4; ++j)
#pragma unroll
                for (int r = 0; r < 4; ++r) s[j][r] *= scale;
        }

        // ---- online softmax (reduce across 16-lane quad) ----
        float mx[4];
#pragma unroll
        for (int r = 0; r < 4; ++r)
            mx[r] = fmaxf(fmaxf(s[0][r], s[1][r]), fmaxf(s[2][r], s[3][r]));
#pragma unroll
        for (int d = 1; d < 16; d <<= 1)
#pragma unroll
            for (int r = 0; r < 4; ++r)
                mx[r] = fmaxf(mx[r], __shfl_xor(mx[r], d));

        float al[4], rs[4];
#pragma unroll
        for (int r = 0; r < 4; ++r) {
            float mn = fmaxf(mrow[r], mx[r]);
            al[r] = __expf(mrow[r] - mn);
            mrow[r] = mn;
            float p0 = __expf(s[0][r] - mn);
            float p1 = __expf(s[1][r] - mn);
            float p2 = __expf(s[2][r] - mn);
            float p3 = __expf(s[3][r] - mn);
            s[0][r] = p0; s[1][r] = p1; s[2][r] = p2; s[3][r] = p3;
            rs[r] = (p0 + p1) + (p2 + p3);
        }
#pragma unroll
        for (int d = 1; d < 16; d <<= 1)
#pragma unroll
            for (int r = 0; r < 4; ++r)
                rs[r] += __shfl_xor(rs[r], d);
#pragma unroll
        for (int r = 0; r < 4; ++r) lrow[r] = lrow[r] * al[r] + rs[r];

        // ---- rescale O, P -> LDS (wave-private strip) ----
#pragma unroll
        for (int j = 0; j < 4; ++j)
#pragma unroll
            for (int r = 0; r < 4; ++r) {
                od[j][r] *= al[r];
                Ps[16 * w + 4 * quad + r][16 * j + ln] = f2bf(s[j][r]);
            }

        // ---- O += P V ----
        bf16x8 pa0 = *(const bf16x8*)&Ps[16 * w + ln][8 * quad];
        bf16x8 pa1 = *(const bf16x8*)&Ps[16 * w + ln][32 + 8 * quad];
#pragma unroll
        for (int j = 0; j < 4; ++j) {
            bf16x8 vb0 = *(const bf16x8*)&VsT[16 * j + ln][8 * quad];
            bf16x8 vb1 = *(const bf16x8*)&VsT[16 * j + ln][32 + 8 * quad];
            od[j] = __builtin_amdgcn_mfma_f32_16x16x32_bf16(pa0, vb0, od[j], 0, 0, 0);
            od[j] = __builtin_amdgcn_mfma_f32_16x16x32_bf16(pa1, vb1, od[j], 0, 0, 0);
        }
    }

    // ---- write partial (unnormalized O bf16, m/l fp32) ----
    const size_t p = (size_t)b * NCHUNK + f;
#pragma unroll
    for (int j = 0; j < 4; ++j)
#pragma unroll
        for (int r = 0; r < 4; ++r)
            PO[p * 4096 + (size_t)(16 * w + 4 * quad + r) * 64 + 16 * j + ln] =
                f2bf(od[j][r]);
    if (ln == 0) {
#pragma unroll
        for (int r = 0; r < 4; ++r) {
            Pm[p * 64 + 16 * w + 4 * quad + r] = mrow[r];
            Pl[p * 64 + 16 * w + 4 * quad + r] = lrow[r];
        }
    }
}

// ---------------------------------------------------------------------------
// Combine partials.  Grid (T/64, B), 256 thr.  Thread t: row=t>>2,
// cols (t&3)*16..+15.  nchunks = (iq>>2)+1 <= 8.
// ---------------------------------------------------------------------------
__global__ __launch_bounds__(256) void attn_combine(
    const unsigned short* __restrict__ PO, const float* __restrict__ Pm,
    const float* __restrict__ Pl, float* __restrict__ out)
{
    const int iq = blockIdx.x, b = blockIdx.y;
    const int g = iq >> 2;
    const int nch = g + 1;
    const int fbase = 2 * g * (g + 1) + (iq - 4 * g) * (g + 1);
    const int t = threadIdx.x;
    const int row = t >> 2;
    const int c0 = (t & 3) << 4;
    const size_t pbase = (size_t)b * NCHUNK + fbase;

    float M = -INFINITY;
    for (int c = 0; c < nch; ++c)
        M = fmaxf(M, Pm[(pbase + c) * 64 + row]);

    float a[16];
#pragma unroll
    for (int i = 0; i < 16; ++i) a[i] = 0.f;
    float L = 0.f;
    for (int c = 0; c < nch; ++c) {
        size_t p = pbase + c;
        float sc = __expf(Pm[p * 64 + row] - M);
        L += sc * Pl[p * 64 + row];
        const unsigned short* po = &PO[p * 4096 + (size_t)row * 64 + c0];
        bf16x8 v0 = *(const bf16x8*)(po);
        bf16x8 v1 = *(const bf16x8*)(po + 8);
#pragma unroll
        for (int i = 0; i < 8; ++i) {
            a[i]     += sc * bf2f((unsigned short)v0[i]);
            a[8 + i] += sc * bf2f((unsigned short)v1[i]);
        }
    }
    float li = 1.f / L;
    float4 o0, o1, o2, o3;
    o0.x=a[0]*li;  o0.y=a[1]*li;  o0.z=a[2]*li;  o0.w=a[3]*li;
    o1.x=a[4]*li;  o1.y=a[5]*li;  o1.z=a[6]*li;  o1.w=a[7]*li;
    o2.x=a[8]*li;  o2.y=a[9]*li;  o2.z=a[10]*li; o2.w=a[11]*li;
    o3.x=a[12]*li; o3.y=a[13]*li; o3.z=a[14]*li; o3.w=a[15]*li;
    float* op = &out[((size_t)b * TDIM + (size_t)iq * 64 + row) * HDIM + c0];
    *(float4*)(op)      = o0;
    *(float4*)(op + 4)  = o1;
    *(float4*)(op + 8)  = o2;
    *(float4*)(op + 12) = o3;
}

extern "C" void kernel_launch(void* const* d_in, const int* in_sizes, int n_in,
                              void* d_out, int out_size, void* d_ws, size_t ws_size,
                              hipStream_t stream) {
    const float* x  = (const float*)d_in[0];
    const float* Wq = (const float*)d_in[1];
    const float* bq = (const float*)d_in[2];
    const float* Wk = (const float*)d_in[3];
    const float* bk = (const float*)d_in[4];
    const float* Wv = (const float*)d_in[5];
    const float* bv = (const float*)d_in[6];
    float* out = (float*)d_out;

    const size_t n = (size_t)BDIM * TDIM * HDIM;     // 1,048,576
    unsigned short* Qb  = (unsigned short*)d_ws;
    unsigned short* Kb  = Qb + n;
    unsigned short* VbT = Kb + n;
    unsigned short* WqT = VbT + n;
    unsigned short* WkT = WqT + (size_t)EDIM * HDIM;
    unsigned short* WvT = WkT + (size_t)EDIM * HDIM;
    unsigned short* PO  = WvT + (size_t)EDIM * HDIM;           // 1152*4096 bf16
    float* Pm = (float*)(PO + (size_t)BDIM * NCHUNK * 4096);   // 1152*64
    float* Pl = Pm + (size_t)BDIM * NCHUNK * 64;

    prep_w<<<dim3(EDIM * HDIM / 256), 256, 0, stream>>>(Wq, Wk, Wv, WqT, WkT, WvT);
    proj_kernel<<<dim3(3 * BDIM * TDIM / 64), 256, 0, stream>>>(
        x, WqT, WkT, WvT, bq, bk, bv, Qb, Kb, VbT);
    attn_partial<<<dim3(NCHUNK, BDIM), 256, 0, stream>>>(Qb, Kb, VbT, PO, Pm, Pl);
    attn_combine<<<dim3(TDIM / 64, BDIM), 256, 0, stream>>>(PO, Pm, Pl, out);
}

// Round 8
// 148.427 us; speedup vs baseline: 1.0500x; 1.0500x over previous
//
#include <hip/hip_runtime.h>
#include <math.h>
#include <stdint.h>

#define BDIM 8
#define TDIM 2048
#define EDIM 1024
#define HDIM 64
#define NCHUNK 144   // sum over iq of ceil((iq+1)/4), iq in [0,32)

typedef short bf16x8 __attribute__((ext_vector_type(8)));   // 8 bf16 (4 VGPRs)
typedef float f32x4 __attribute__((ext_vector_type(4)));    // 4 fp32 acc

__device__ __forceinline__ unsigned short f2bf(float f) {   // RNE fp32->bf16
    uint32_t u = __builtin_bit_cast(uint32_t, f);
    u += 0x7fffu + ((u >> 16) & 1u);
    return (unsigned short)(u >> 16);
}
__device__ __forceinline__ float bf2f(unsigned short s) {
    uint32_t u = ((uint32_t)s) << 16;
    return __builtin_bit_cast(float, u);
}

// ---------------------------------------------------------------------------
// prep_w: W[e][h] fp32 -> WT[h][e] bf16.  Kept as a separate coalesced pass:
// inline transpose in proj would need 16x ds_write_b16 scatter (measured
// pathology).  ~2 us.
// ---------------------------------------------------------------------------
__global__ __launch_bounds__(256) void prep_w(
    const float* __restrict__ Wq, const float* __restrict__ Wk,
    const float* __restrict__ Wv,
    unsigned short* __restrict__ WqT, unsigned short* __restrict__ WkT,
    unsigned short* __restrict__ WvT)
{
    int id = blockIdx.x * 256 + threadIdx.x;   // 0..65535
    int e = id >> 6, h = id & 63;              // coalesced reads
    int oi = h * EDIM + e;
    WqT[oi] = f2bf(Wq[id]);
    WkT[oi] = f2bf(Wk[id]);
    WvT[oi] = f2bf(Wv[id]);
}

// ---------------------------------------------------------------------------
// proj (round-6 monolithic — best measured).  Grid 256 blocks, 256 thr.
// 1 block/CU -> ILP pipeline: double-buffer ALL LDS tiles (x + 3 W =
// 73.7 KB), register prefetch during MFMA, ONE barrier per K-iter.
// Q,K row-major [b*T][h]; V TRANSPOSED [b][d][T].
// ---------------------------------------------------------------------------
__global__ __launch_bounds__(256) void proj_kernel(
    const float* __restrict__ x,
    const unsigned short* __restrict__ WqT, const unsigned short* __restrict__ WkT,
    const unsigned short* __restrict__ WvT,
    const float* __restrict__ bq, const float* __restrict__ bk,
    const float* __restrict__ bv,
    unsigned short* __restrict__ Qb, unsigned short* __restrict__ Kb,
    unsigned short* __restrict__ VbT)
{
    __shared__ unsigned short Xs[2][64][72];   // row stride 144B (16B mult)
    __shared__ unsigned short Wqs[2][64][72];
    __shared__ unsigned short Wks[2][64][72];
    __shared__ unsigned short Wvs[2][64][72];

    const int t = threadIdx.x;
    const int lane = t & 63, w = t >> 6, quad = lane >> 4, ln = lane & 15;
    const int row0 = blockIdx.x * 64;
    const int sr = t >> 2;              // staging row 0..63
    const int sc = (t & 3) << 4;        // staging col 0,16,32,48

    f32x4 accq[4], acck[4], accv[4];
#pragma unroll
    for (int j = 0; j < 4; ++j) {
        accq[j] = (f32x4)(0.f); acck[j] = (f32x4)(0.f); accv[j] = (f32x4)(0.f);
    }

    const float* xp0  = &x[(size_t)(row0 + sr) * EDIM + sc];
    const size_t wrow = (size_t)sr * EDIM + sc;

    // ---- preload tile 0 into buf 0 ----
    {
        float4 x0 = *(const float4*)(xp0);
        float4 x1 = *(const float4*)(xp0 + 4);
        float4 x2 = *(const float4*)(xp0 + 8);
        float4 x3 = *(const float4*)(xp0 + 12);
        bf16x8 xb0, xb1;
        xb0[0]=(short)f2bf(x0.x); xb0[1]=(short)f2bf(x0.y); xb0[2]=(short)f2bf(x0.z); xb0[3]=(short)f2bf(x0.w);
        xb0[4]=(short)f2bf(x1.x); xb0[5]=(short)f2bf(x1.y); xb0[6]=(short)f2bf(x1.z); xb0[7]=(short)f2bf(x1.w);
        xb1[0]=(short)f2bf(x2.x); xb1[1]=(short)f2bf(x2.y); xb1[2]=(short)f2bf(x2.z); xb1[3]=(short)f2bf(x2.w);
        xb1[4]=(short)f2bf(x3.x); xb1[5]=(short)f2bf(x3.y); xb1[6]=(short)f2bf(x3.z); xb1[7]=(short)f2bf(x3.w);
        *(bf16x8*)&Xs[0][sr][sc]     = xb0;
        *(bf16x8*)&Xs[0][sr][sc + 8] = xb1;
        *(bf16x8*)&Wqs[0][sr][sc]     = *(const bf16x8*)&WqT[wrow];
        *(bf16x8*)&Wqs[0][sr][sc + 8] = *(const bf16x8*)&WqT[wrow + 8];
        *(bf16x8*)&Wks[0][sr][sc]     = *(const bf16x8*)&WkT[wrow];
        *(bf16x8*)&Wks[0][sr][sc + 8] = *(const bf16x8*)&WkT[wrow + 8];
        *(bf16x8*)&Wvs[0][sr][sc]     = *(const bf16x8*)&WvT[wrow];
        *(bf16x8*)&Wvs[0][sr][sc + 8] = *(const bf16x8*)&WvT[wrow + 8];
    }

    for (int kt = 0; kt < EDIM / 64; ++kt) {
        const int cur = kt & 1, nxt = cur ^ 1;

        // ---- issue next-tile global loads (in flight during MFMA) ----
        float4 x0, x1, x2, x3;
        bf16x8 wq0, wq1, wk0, wk1, wv0, wv1;
        if (kt < 15) {
            const float* xp = xp0 + (kt + 1) * 64;
            x0 = *(const float4*)(xp);
            x1 = *(const float4*)(xp + 4);
            x2 = *(const float4*)(xp + 8);
            x3 = *(const float4*)(xp + 12);
            const size_t wo = wrow + (kt + 1) * 64;
            wq0 = *(const bf16x8*)&WqT[wo];
            wq1 = *(const bf16x8*)&WqT[wo + 8];
            wk0 = *(const bf16x8*)&WkT[wo];
            wk1 = *(const bf16x8*)&WkT[wo + 8];
            wv0 = *(const bf16x8*)&WvT[wo];
            wv1 = *(const bf16x8*)&WvT[wo + 8];
        }

        __syncthreads();   // buf[cur] fully written (prev iter / preload)

        bf16x8 xa0 = *(const bf16x8*)&Xs[cur][16 * w + ln][8 * quad];
        bf16x8 xa1 = *(const bf16x8*)&Xs[cur][16 * w + ln][32 + 8 * quad];
#pragma unroll
        for (int j = 0; j < 4; ++j) {
            bf16x8 w0, w1;
            w0 = *(const bf16x8*)&Wqs[cur][16 * j + ln][8 * quad];
            w1 = *(const bf16x8*)&Wqs[cur][16 * j + ln][32 + 8 * quad];
            accq[j] = __builtin_amdgcn_mfma_f32_16x16x32_bf16(xa0, w0, accq[j], 0, 0, 0);
            accq[j] = __builtin_amdgcn_mfma_f32_16x16x32_bf16(xa1, w1, accq[j], 0, 0, 0);
            w0 = *(const bf16x8*)&Wks[cur][16 * j + ln][8 * quad];
            w1 = *(const bf16x8*)&Wks[cur][16 * j + ln][32 + 8 * quad];
            acck[j] = __builtin_amdgcn_mfma_f32_16x16x32_bf16(xa0, w0, acck[j], 0, 0, 0);
            acck[j] = __builtin_amdgcn_mfma_f32_16x16x32_bf16(xa1, w1, acck[j], 0, 0, 0);
            w0 = *(const bf16x8*)&Wvs[cur][16 * j + ln][8 * quad];
            w1 = *(const bf16x8*)&Wvs[cur][16 * j + ln][32 + 8 * quad];
            accv[j] = __builtin_amdgcn_mfma_f32_16x16x32_bf16(xa0, w0, accv[j], 0, 0, 0);
            accv[j] = __builtin_amdgcn_mfma_f32_16x16x32_bf16(xa1, w1, accv[j], 0, 0, 0);
        }

        // ---- convert + write next tile to alternate buffer (safe: all
        //      buf[nxt] readers passed this iteration's barrier) ----
        if (kt < 15) {
            bf16x8 xb0, xb1;
            xb0[0]=(short)f2bf(x0.x); xb0[1]=(short)f2bf(x0.y); xb0[2]=(short)f2bf(x0.z); xb0[3]=(short)f2bf(x0.w);
            xb0[4]=(short)f2bf(x1.x); xb0[5]=(short)f2bf(x1.y); xb0[6]=(short)f2bf(x1.z); xb0[7]=(short)f2bf(x1.w);
            xb1[0]=(short)f2bf(x2.x); xb1[1]=(short)f2bf(x2.y); xb1[2]=(short)f2bf(x2.z); xb1[3]=(short)f2bf(x2.w);
            xb1[4]=(short)f2bf(x3.x); xb1[5]=(short)f2bf(x3.y); xb1[6]=(short)f2bf(x3.z); xb1[7]=(short)f2bf(x3.w);
            *(bf16x8*)&Xs[nxt][sr][sc]     = xb0;
            *(bf16x8*)&Xs[nxt][sr][sc + 8] = xb1;
            *(bf16x8*)&Wqs[nxt][sr][sc]     = wq0;
            *(bf16x8*)&Wqs[nxt][sr][sc + 8] = wq1;
            *(bf16x8*)&Wks[nxt][sr][sc]     = wk0;
            *(bf16x8*)&Wks[nxt][sr][sc + 8] = wk1;
            *(bf16x8*)&Wvs[nxt][sr][sc]     = wv0;
            *(bf16x8*)&Wvs[nxt][sr][sc + 8] = wv1;
        }
    }

    // epilogue: bias + bf16 store (C/D layout: row=4*quad+reg, col=ln+16j)
#pragma unroll
    for (int j = 0; j < 4; ++j) {
        int col = 16 * j + ln;
        float bqv = bq[col], bkv = bk[col], bvv = bv[col];
#pragma unroll
        for (int r = 0; r < 4; ++r) {
            size_t row = (size_t)(row0 + 16 * w + 4 * quad + r);
            Qb[row * HDIM + col] = f2bf(accq[j][r] + bqv);
            Kb[row * HDIM + col] = f2bf(acck[j][r] + bkv);
            int bb = (int)(row >> 11);            // row / TDIM
            int tr = (int)(row & 2047);           // row % TDIM
            VbT[((size_t)bb * HDIM + col) * TDIM + tr] = f2bf(accv[j][r] + bvv);
        }
    }
}

// ---------------------------------------------------------------------------
// Split-K flash partial, PIPELINED: double-buffered Ks/VsT (LDS 46 KB,
// 3 blocks/CU), register prefetch of next K/V tile before the barrier,
// ONE barrier per iteration — global latency hidden under MFMA+softmax.
// Grid (NCHUNK=144, B).  Partials PO stored bf16.
// ---------------------------------------------------------------------------
__global__ __launch_bounds__(256) void attn_partial(
    const unsigned short* __restrict__ Qb, const unsigned short* __restrict__ Kb,
    const unsigned short* __restrict__ VbT,
    unsigned short* __restrict__ PO, float* __restrict__ Pm, float* __restrict__ Pl)
{
    __shared__ unsigned short Ks[2][64][72];
    __shared__ unsigned short VsT[2][64][72];   // [d][k]
    __shared__ unsigned short Ps[64][72];       // [q][k] bf16, wave-private

    const int t = threadIdx.x;
    const int lane = t & 63, w = t >> 6, quad = lane >> 4, ln = lane & 15;
    const int f = blockIdx.x;
    const int b = blockIdx.y;

    // decode (iq, chunk) from f: group g = iq>>2 has (g+1) chunks/q-tile
    int g = 0;
    while (f >= 2 * (g + 1) * (g + 2)) ++g;       // g in 0..7
    const int r_  = f - 2 * g * (g + 1);
    const int iq  = 4 * g + r_ / (g + 1);
    const int ch  = r_ % (g + 1);

    const int q0 = iq * 64;
    const size_t base = (size_t)b * TDIM * HDIM;
    const int sr = t >> 2;
    const int sc = (t & 3) << 4;

    const size_t qrow = base + (size_t)(q0 + 16 * w + ln) * HDIM;
    bf16x8 qa0 = *(const bf16x8*)&Qb[qrow + 8 * quad];
    bf16x8 qa1 = *(const bf16x8*)&Qb[qrow + 32 + 8 * quad];

    f32x4 od[4];
#pragma unroll
    for (int j = 0; j < 4; ++j) od[j] = (f32x4)(0.f);
    float mrow[4], lrow[4];
#pragma unroll
    for (int r = 0; r < 4; ++r) { mrow[r] = -INFINITY; lrow[r] = 0.f; }

    const float scale = 0.125f;   // 1/sqrt(64)
    const int jt0 = 4 * ch;
    int j1 = jt0 + 3; if (j1 > iq) j1 = iq;

    // ---- preload tile jt0 into buf 0 ----
    {
        size_t ko = base + (size_t)(jt0 * 64 + sr) * HDIM + sc;
        *(bf16x8*)&Ks[0][sr][sc]     = *(const bf16x8*)&Kb[ko];
        *(bf16x8*)&Ks[0][sr][sc + 8] = *(const bf16x8*)&Kb[ko + 8];
        const unsigned short* vrow =
            &VbT[((size_t)b * HDIM + sr) * TDIM + jt0 * 64 + sc];
        *(bf16x8*)&VsT[0][sr][sc]     = *(const bf16x8*)vrow;
        *(bf16x8*)&VsT[0][sr][sc + 8] = *(const bf16x8*)(vrow + 8);
    }

    for (int jt = jt0; jt <= j1; ++jt) {
        const int cur = (jt - jt0) & 1, nxt = cur ^ 1;

        // ---- issue next-tile global loads (fly during compute) ----
        bf16x8 kn0, kn1, vn0, vn1;
        if (jt < j1) {
            size_t ko = base + (size_t)((jt + 1) * 64 + sr) * HDIM + sc;
            kn0 = *(const bf16x8*)&Kb[ko];
            kn1 = *(const bf16x8*)&Kb[ko + 8];
            const unsigned short* vrow =
                &VbT[((size_t)b * HDIM + sr) * TDIM + (jt + 1) * 64 + sc];
            vn0 = *(const bf16x8*)vrow;
            vn1 = *(const bf16x8*)(vrow + 8);
        }

        __syncthreads();   // buf[cur] ready; prev readers of buf[nxt] done

        // ---- S = Q K^T ----
        f32x4 s[4];
#pragma unroll
        for (int j = 0; j < 4; ++j) {
            bf16x8 kb0 = *(const bf16x8*)&Ks[cur][16 * j + ln][8 * quad];
            bf16x8 kb1 = *(const bf16x8*)&Ks[cur][16 * j + ln][32 + 8 * quad];
            s[j] = (f32x4)(0.f);
            s[j] = __builtin_amdgcn_mfma_f32_16x16x32_bf16(qa0, kb0, s[j], 0, 0, 0);
            s[j] = __builtin_amdgcn_mfma_f32_16x16x32_bf16(qa1, kb1, s[j], 0, 0, 0);
        }

        // ---- scale + causal mask (diagonal tile only) ----
        if (jt == iq) {
#pragma unroll
            for (int j = 0; j < 4; ++j) {
                int kg = jt * 64 + 16 * j + ln;
#pragma unroll
                for (int r = 0; r < 4; ++r) {
                    int qg = q0 + 16 * w + 4 * quad + r;
                    s[j][r] = (kg <= qg) ? s[j][r] * scale : -INFINITY;
                }
            }
        } else {
#pragma unroll
            for (int j = 0; j < 4; ++j)
#pragma unroll
                for (int r = 0; r < 4; ++r) s[j][r] *= scale;
        }

        // ---- online softmax (reduce across 16-lane quad) ----
        float mx[4];
#pragma unroll
        for (int r = 0; r < 4; ++r)
            mx[r] = fmaxf(fmaxf(s[0][r], s[1][r]), fmaxf(s[2][r], s[3][r]));
#pragma unroll
        for (int d = 1; d < 16; d <<= 1)
#pragma unroll
            for (int r = 0; r < 4; ++r)
                mx[r] = fmaxf(mx[r], __shfl_xor(mx[r], d));

        float al[4], rs[4];
#pragma unroll
        for (int r = 0; r < 4; ++r) {
            float mn = fmaxf(mrow[r], mx[r]);
            al[r] = __expf(mrow[r] - mn);
            mrow[r] = mn;
            float p0 = __expf(s[0][r] - mn);
            float p1 = __expf(s[1][r] - mn);
            float p2 = __expf(s[2][r] - mn);
            float p3 = __expf(s[3][r] - mn);
            s[0][r] = p0; s[1][r] = p1; s[2][r] = p2; s[3][r] = p3;
            rs[r] = (p0 + p1) + (p2 + p3);
        }
#pragma unroll
        for (int d = 1; d < 16; d <<= 1)
#pragma unroll
            for (int r = 0; r < 4; ++r)
                rs[r] += __shfl_xor(rs[r], d);
#pragma unroll
        for (int r = 0; r < 4; ++r) lrow[r] = lrow[r] * al[r] + rs[r];

        // ---- rescale O, P -> LDS (wave-private strip, no barrier) ----
#pragma unroll
        for (int j = 0; j < 4; ++j)
#pragma unroll
            for (int r = 0; r < 4; ++r) {
                od[j][r] *= al[r];
                Ps[16 * w + 4 * quad + r][16 * j + ln] = f2bf(s[j][r]);
            }

        // ---- O += P V ----
        bf16x8 pa0 = *(const bf16x8*)&Ps[16 * w + ln][8 * quad];
        bf16x8 pa1 = *(const bf16x8*)&Ps[16 * w + ln][32 + 8 * quad];
#pragma unroll
        for (int j = 0; j < 4; ++j) {
            bf16x8 vb0 = *(const bf16x8*)&VsT[cur][16 * j + ln][8 * quad];
            bf16x8 vb1 = *(const bf16x8*)&VsT[cur][16 * j + ln][32 + 8 * quad];
            od[j] = __builtin_amdgcn_mfma_f32_16x16x32_bf16(pa0, vb0, od[j], 0, 0, 0);
            od[j] = __builtin_amdgcn_mfma_f32_16x16x32_bf16(pa1, vb1, od[j], 0, 0, 0);
        }

        // ---- write next tile to alternate buffer ----
        if (jt < j1) {
            *(bf16x8*)&Ks[nxt][sr][sc]     = kn0;
            *(bf16x8*)&Ks[nxt][sr][sc + 8] = kn1;
            *(bf16x8*)&VsT[nxt][sr][sc]     = vn0;
            *(bf16x8*)&VsT[nxt][sr][sc + 8] = vn1;
        }
    }

    // ---- write partial (unnormalized O bf16, m/l fp32) ----
    const size_t p = (size_t)b * NCHUNK + f;
#pragma unroll
    for (int j = 0; j < 4; ++j)
#pragma unroll
        for (int r = 0; r < 4; ++r)
            PO[p * 4096 + (size_t)(16 * w + 4 * quad + r) * 64 + 16 * j + ln] =
                f2bf(od[j][r]);
    if (ln == 0) {
#pragma unroll
        for (int r = 0; r < 4; ++r) {
            Pm[p * 64 + 16 * w + 4 * quad + r] = mrow[r];
            Pl[p * 64 + 16 * w + 4 * quad + r] = lrow[r];
        }
    }
}

// ---------------------------------------------------------------------------
// Combine partials.  Grid (T/64, B), 256 thr.  Thread t: row=t>>2,
// cols (t&3)*16..+15.  nchunks = (iq>>2)+1 <= 8.
// ---------------------------------------------------------------------------
__global__ __launch_bounds__(256) void attn_combine(
    const unsigned short* __restrict__ PO, const float* __restrict__ Pm,
    const float* __restrict__ Pl, float* __restrict__ out)
{
    const int iq = blockIdx.x, b = blockIdx.y;
    const int g = iq >> 2;
    const int nch = g + 1;
    const int fbase = 2 * g * (g + 1) + (iq - 4 * g) * (g + 1);
    const int t = threadIdx.x;
    const int row = t >> 2;
    const int c0 = (t & 3) << 4;
    const size_t pbase = (size_t)b * NCHUNK + fbase;

    float M = -INFINITY;
    for (int c = 0; c < nch; ++c)
        M = fmaxf(M, Pm[(pbase + c) * 64 + row]);

    float a[16];
#pragma unroll
    for (int i = 0; i < 16; ++i) a[i] = 0.f;
    float L = 0.f;
    for (int c = 0; c < nch; ++c) {
        size_t p = pbase + c;
        float sc = __expf(Pm[p * 64 + row] - M);
        L += sc * Pl[p * 64 + row];
        const unsigned short* po = &PO[p * 4096 + (size_t)row * 64 + c0];
        bf16x8 v0 = *(const bf16x8*)(po);
        bf16x8 v1 = *(const bf16x8*)(po + 8);
#pragma unroll
        for (int i = 0; i < 8; ++i) {
            a[i]     += sc * bf2f((unsigned short)v0[i]);
            a[8 + i] += sc * bf2f((unsigned short)v1[i]);
        }
    }
    float li = 1.f / L;
    float4 o0, o1, o2, o3;
    o0.x=a[0]*li;  o0.y=a[1]*li;  o0.z=a[2]*li;  o0.w=a[3]*li;
    o1.x=a[4]*li;  o1.y=a[5]*li;  o1.z=a[6]*li;  o1.w=a[7]*li;
    o2.x=a[8]*li;  o2.y=a[9]*li;  o2.z=a[10]*li; o2.w=a[11]*li;
    o3.x=a[12]*li; o3.y=a[13]*li; o3.z=a[14]*li; o3.w=a[15]*li;
    float* op = &out[((size_t)b * TDIM + (size_t)iq * 64 + row) * HDIM + c0];
    *(float4*)(op)      = o0;
    *(float4*)(op + 4)  = o1;
    *(float4*)(op + 8)  = o2;
    *(float4*)(op + 12) = o3;
}

extern "C" void kernel_launch(void* const* d_in, const int* in_sizes, int n_in,
                              void* d_out, int out_size, void* d_ws, size_t ws_size,
                              hipStream_t stream) {
    const float* x  = (const float*)d_in[0];
    const float* Wq = (const float*)d_in[1];
    const float* bq = (const float*)d_in[2];
    const float* Wk = (const float*)d_in[3];
    const float* bk = (const float*)d_in[4];
    const float* Wv = (const float*)d_in[5];
    const float* bv = (const float*)d_in[6];
    float* out = (float*)d_out;

    const size_t n = (size_t)BDIM * TDIM * HDIM;     // 1,048,576
    unsigned short* Qb  = (unsigned short*)d_ws;
    unsigned short* Kb  = Qb + n;
    unsigned short* VbT = Kb + n;
    unsigned short* WqT = VbT + n;
    unsigned short* WkT = WqT + (size_t)EDIM * HDIM;
    unsigned short* WvT = WkT + (size_t)EDIM * HDIM;
    unsigned short* PO  = WvT + (size_t)EDIM * HDIM;           // 1152*4096 bf16
    float* Pm = (float*)(PO + (size_t)BDIM * NCHUNK * 4096);   // 1152*64
    float* Pl = Pm + (size_t)BDIM * NCHUNK * 64;

    prep_w<<<dim3(EDIM * HDIM / 256), 256, 0, stream>>>(Wq, Wk, Wv, WqT, WkT, WvT);
    proj_kernel<<<dim3(BDIM * TDIM / 64), 256, 0, stream>>>(
        x, WqT, WkT, WvT, bq, bk, bv, Qb, Kb, VbT);
    attn_partial<<<dim3(NCHUNK, BDIM), 256, 0, stream>>>(Qb, Kb, VbT, PO, Pm, Pl);
    attn_combine<<<dim3(TDIM / 64, BDIM), 256, 0, stream>>>(PO, Pm, Pl, out);
}